// Round 1
// baseline (1398.639 us; speedup 1.0000x reference)
//
#include <hip/hip_runtime.h>

// NMS filter: B=8 batches, C=20 classes, N=2048 boxes.
// One workgroup per (b,c): bitonic-sort scores desc (stable via composite key),
// greedy NMS in 64-box chunks (wave0 resolves chunk, all threads sweep tail),
// scatter conf*keep back to original order.

#define BB   8
#define CC   20
#define NBOX 2048
#define NMS_THR 0.45f
#define PRE_THR 0.005f

typedef unsigned long long u64;
typedef unsigned int u32;

__global__ __launch_bounds__(256) void nms_kernel(const float* __restrict__ bbs,
                                                  const float* __restrict__ conf,
                                                  float* __restrict__ out) {
    const int wg   = blockIdx.x;          // 0..159 = b*CC + c
    const int b    = wg / CC;
    const int base = wg * NBOX;           // conf/out flat base
    const int tid  = threadIdx.x;

    __shared__ union {
        u64 keys[NBOX];                   // 16 KB (sort phase)
        struct {                          // 48 KB (NMS phase) — aliased after sort
            float sx1[NBOX]; float sy1[NBOX];
            float sx2[NBOX]; float sy2[NBOX];
            float sar[NBOX]; float scf[NBOX];
        } a;
    } u;
    __shared__ int           sidx[NBOX];  // 8 KB  original index per sorted rank
    __shared__ unsigned char skeep[NBOX]; // 2 KB  keep flag per sorted rank
    __shared__ u64           s_mask;      // alive mask of current chunk

    // ---- 1. build composite sort keys: conf desc, tie -> original idx asc ----
    // conf in [0,1) => non-negative => f32 bit pattern is order-monotonic.
    for (int n = tid; n < NBOX; n += 256) {
        float cv = conf[base + n];
        u.keys[n] = ((u64)__float_as_uint(cv) << 32) | (u32)(~n);
    }
    __syncthreads();

    // ---- 2. bitonic sort, DESCENDING (swap if (a<b) in "up" region) ----
    for (int k = 2; k <= NBOX; k <<= 1) {
        for (int j = k >> 1; j > 0; j >>= 1) {
            for (int i = tid; i < NBOX; i += 256) {
                int ixj = i ^ j;
                if (ixj > i) {
                    u64 a = u.keys[i], c2 = u.keys[ixj];
                    bool up = ((i & k) == 0);
                    if ((a < c2) == up) { u.keys[i] = c2; u.keys[ixj] = a; }
                }
            }
            __syncthreads();
        }
    }

    // ---- 3. pull keys to registers, then overwrite union with box arrays ----
    u64 myk[8];
    #pragma unroll
    for (int p = 0; p < 8; ++p) myk[p] = u.keys[tid + p * 256];
    __syncthreads();

    #pragma unroll
    for (int p = 0; p < 8; ++p) {
        int r   = tid + p * 256;
        u64 key = myk[p];
        int idx = (int)(~(u32)key) & (NBOX - 1);     // recover original index
        float cv = __uint_as_float((u32)(key >> 32));
        float4 bv = ((const float4*)bbs)[b * NBOX + idx];
        float x1 = bv.x, y1 = bv.y, x2 = bv.z, y2 = bv.w;
        u.a.sx1[r] = x1; u.a.sy1[r] = y1;
        u.a.sx2[r] = x2; u.a.sy2[r] = y2;
        u.a.sar[r] = fmaxf(x2 - x1, 0.f) * fmaxf(y2 - y1, 0.f);
        u.a.scf[r] = cv;
        sidx[r]  = idx;
        skeep[r] = (cv > PRE_THR) ? 1 : 0;           // pre-threshold (strict >)
    }
    __syncthreads();

    // ---- 4. greedy NMS in 64-box chunks ----
    for (int cb = 0; cb < NBOX; cb += 64) {
        // Phase A: wave 0 resolves within-chunk suppression sequentially.
        if (tid < 64) {
            int lane = tid;
            int r = cb + lane;
            float bx1 = u.a.sx1[r], by1 = u.a.sy1[r];
            float bx2 = u.a.sx2[r], by2 = u.a.sy2[r];
            float bar = u.a.sar[r];
            bool k = (skeep[r] != 0);
            u64 alive = __ballot(k);
            #pragma unroll 1
            for (int l = 0; l < 63; ++l) {
                if ((alive >> l) & 1ull) {           // uniform scalar branch
                    float px1 = __shfl(bx1, l);
                    float py1 = __shfl(by1, l);
                    float px2 = __shfl(bx2, l);
                    float py2 = __shfl(by2, l);
                    float par = __shfl(bar, l);
                    if (lane > l && k) {
                        float iw = fmaxf(fminf(px2, bx2) - fmaxf(px1, bx1), 0.f);
                        float ih = fmaxf(fminf(py2, by2) - fmaxf(py1, by1), 0.f);
                        float inter = iw * ih;
                        float den = fmaxf(par + bar - inter, 1e-12f);
                        float iou = inter / den;     // IEEE f32 div, matches ref
                        if (iou > NMS_THR) k = false;
                    }
                    alive = __ballot(k);
                }
            }
            skeep[r] = k ? 1 : 0;
            if (lane == 0) s_mask = alive;
        }
        __syncthreads();

        // Phase B: all 256 threads suppress the tail vs this chunk's survivors.
        u64 mask = s_mask;
        if (mask) {
            for (int jj = cb + 64 + tid; jj < NBOX; jj += 256) {
                if (skeep[jj]) {
                    float jx1 = u.a.sx1[jj], jy1 = u.a.sy1[jj];
                    float jx2 = u.a.sx2[jj], jy2 = u.a.sy2[jj];
                    float jar = u.a.sar[jj];
                    u64 m = mask;
                    bool dead = false;
                    while (m) {
                        int l = __ffsll(m) - 1;
                        m &= m - 1;
                        int r = cb + l;
                        float iw = fmaxf(fminf(u.a.sx2[r], jx2) - fmaxf(u.a.sx1[r], jx1), 0.f);
                        float ih = fmaxf(fminf(u.a.sy2[r], jy2) - fmaxf(u.a.sy1[r], jy1), 0.f);
                        float inter = iw * ih;
                        float den = fmaxf(u.a.sar[r] + jar - inter, 1e-12f);
                        float iou = inter / den;
                        if (iou > NMS_THR) { dead = true; break; }
                    }
                    if (dead) skeep[jj] = 0;
                }
            }
        }
        __syncthreads();
    }

    // ---- 5. scatter: out[orig_idx] = kept ? conf : 0 ----
    #pragma unroll
    for (int p = 0; p < 8; ++p) {
        int r = tid + p * 256;
        out[base + sidx[r]] = skeep[r] ? u.a.scf[r] : 0.0f;
    }
}

extern "C" void kernel_launch(void* const* d_in, const int* in_sizes, int n_in,
                              void* d_out, int out_size, void* d_ws, size_t ws_size,
                              hipStream_t stream) {
    const float* bbs  = (const float*)d_in[0];   // [B, N, 4] f32
    const float* conf = (const float*)d_in[1];   // [B, C, N] f32
    float* out = (float*)d_out;                  // [B, C, N] f32
    nms_kernel<<<dim3(BB * CC), dim3(256), 0, stream>>>(bbs, conf, out);
}

// Round 2
// 1132.413 us; speedup vs baseline: 1.2351x; 1.2351x over previous
//
#include <hip/hip_runtime.h>

// NMS filter: B=8, C=20, N=2048. One WG per (b,c).
// R2: precomputed within-chunk suppression bitmasks + branchless closure +
// pipelined (no-break) tail sweep + pair-enumerated bitonic sort.

#define BB   8
#define CC   20
#define NBOX 2048
#define NCHUNK (NBOX / 64)
#define NMS_THR 0.45f
#define PRE_THR 0.005f

typedef unsigned long long u64;
typedef unsigned int u32;

// Exact-rounding IoU pieces (avoid fp-contract changing rounding vs reference).
__device__ __forceinline__ float area_rn(float x1, float y1, float x2, float y2) {
    return __fmul_rn(fmaxf(__fsub_rn(x2, x1), 0.f), fmaxf(__fsub_rn(y2, y1), 0.f));
}

__global__ __launch_bounds__(256) void nms_kernel(const float* __restrict__ bbs,
                                                  const float* __restrict__ conf,
                                                  float* __restrict__ out) {
    const int wg   = blockIdx.x;
    const int b    = wg / CC;
    const int base = wg * NBOX;
    const int tid  = threadIdx.x;
    const int lane = tid & 63;
    const int wv   = tid >> 6;

    __shared__ union {
        u64 keys[NBOX];                               // 16 KB (sort phase)
        struct { float x1[NBOX], y1[NBOX], x2[NBOX], y2[NBOX]; } a;  // 32 KB
    } u;
    __shared__ u64           Mcol[NBOX];              // 16 KB: who rank r suppresses in its chunk
    __shared__ int           sidx[NBOX];              // 8 KB
    __shared__ unsigned char skeep[NBOX];             // 2 KB

    // ---- 1. composite keys: conf desc, tie -> orig idx asc (conf >= 0) ----
    for (int n = tid; n < NBOX; n += 256) {
        float cv = conf[base + n];
        u.keys[n] = ((u64)__float_as_uint(cv) << 32) | (u32)(~n);
    }
    __syncthreads();

    // ---- 2. bitonic sort desc, pair enumeration (N/2 pairs, no divergence) ----
    for (int k = 2; k <= NBOX; k <<= 1) {
        for (int j = k >> 1; j > 0; j >>= 1) {
            const int mask = j - 1;
            for (int t = tid; t < NBOX / 2; t += 256) {
                int i   = ((t & ~mask) << 1) | (t & mask);
                int ip  = i + j;
                u64 a = u.keys[i], c2 = u.keys[ip];
                if ((a < c2) == ((i & k) == 0)) { u.keys[i] = c2; u.keys[ip] = a; }
            }
            __syncthreads();
        }
    }

    // ---- 3. extract keys, fill box arrays, early-write conf to out ----
    u64 myk[8];
    #pragma unroll
    for (int p = 0; p < 8; ++p) myk[p] = u.keys[tid + p * 256];
    __syncthreads();

    #pragma unroll
    for (int p = 0; p < 8; ++p) {
        int r   = tid + p * 256;
        u64 key = myk[p];
        int idx = (int)(~(u32)key) & (NBOX - 1);
        float cv = __uint_as_float((u32)(key >> 32));
        float4 bv = ((const float4*)bbs)[b * NBOX + idx];
        u.a.x1[r] = bv.x; u.a.y1[r] = bv.y; u.a.x2[r] = bv.z; u.a.y2[r] = bv.w;
        sidx[r]  = idx;
        skeep[r] = (cv > PRE_THR) ? 1 : 0;
        out[base + idx] = cv;                         // zeroed later if suppressed
    }
    __syncthreads();

    // ---- 4. precompute within-chunk suppression masks (4 waves x 8 chunks) ----
    for (int c = wv; c < NCHUNK; c += 4) {
        int r = c * 64 + lane;
        float bx1 = u.a.x1[r], by1 = u.a.y1[r], bx2 = u.a.x2[r], by2 = u.a.y2[r];
        float bar = area_rn(bx1, by1, bx2, by2);
        u64 col = 0;
        #pragma unroll 7
        for (int s = 1; s < 64; ++s) {
            int src = (lane + s) & 63;
            float px1 = __shfl(bx1, src), py1 = __shfl(by1, src);
            float px2 = __shfl(bx2, src), py2 = __shfl(by2, src);
            float par = area_rn(px1, py1, px2, py2);
            float iw = fmaxf(__fsub_rn(fminf(px2, bx2), fmaxf(px1, bx1)), 0.f);
            float ih = fmaxf(__fsub_rn(fminf(py2, by2), fmaxf(py1, by1)), 0.f);
            float inter = __fmul_rn(iw, ih);
            float den = fmaxf(__fsub_rn(__fadd_rn(bar, par), inter), 1e-12f);
            bool sup = (__fdiv_rn(inter, den) > NMS_THR) && (src > lane);
            if (sup) col |= 1ull << src;
        }
        Mcol[r] = col;
    }
    __syncthreads();

    // ---- 5. chunk loop: branchless closure + pipelined tail sweep ----
    for (int cb = 0; cb < NBOX; cb += 64) {
        // closure (each wave computes redundantly; no broadcast needed)
        bool k0 = skeep[cb + lane] != 0;
        u64 alive = __ballot(k0);
        if (alive) {
            #pragma unroll 8
            for (int l = 0; l < 64; ++l) {
                u64 cl   = Mcol[cb + l];
                u64 take = (u64)0 - ((alive >> l) & 1ull);   // all-ones if pivot l alive
                alive &= ~(cl & take);
            }
        }
        if (tid < 64) skeep[cb + lane] = (unsigned char)((alive >> lane) & 1ull);

        if (alive) {
            for (int jb = cb + 64 + wv * 64; jb < NBOX; jb += 256) {
                int jj = jb + lane;
                bool jk = skeep[jj] != 0;
                if (__ballot(jk)) {
                    float jx1 = u.a.x1[jj], jy1 = u.a.y1[jj];
                    float jx2 = u.a.x2[jj], jy2 = u.a.y2[jj];
                    float jar = area_rn(jx1, jy1, jx2, jy2);
                    bool dead = false;
                    u64 m = alive;
                    while (m) {                       // uniform walk over survivors
                        int l = __ffsll(m) - 1;
                        m &= m - 1;
                        int r = cb + l;
                        float px1 = u.a.x1[r], py1 = u.a.y1[r];
                        float px2 = u.a.x2[r], py2 = u.a.y2[r];
                        float par = area_rn(px1, py1, px2, py2);
                        float iw = fmaxf(__fsub_rn(fminf(px2, jx2), fmaxf(px1, jx1)), 0.f);
                        float ih = fmaxf(__fsub_rn(fminf(py2, jy2), fmaxf(py1, jy1)), 0.f);
                        float inter = __fmul_rn(iw, ih);
                        float den = fmaxf(__fsub_rn(__fadd_rn(par, jar), inter), 1e-12f);
                        dead = dead | (__fdiv_rn(inter, den) > NMS_THR);
                    }
                    if (jk && dead) skeep[jj] = 0;
                }
            }
        }
        __syncthreads();
    }

    // ---- 6. zero-out suppressed entries ----
    #pragma unroll
    for (int p = 0; p < 8; ++p) {
        int r = tid + p * 256;
        if (!skeep[r]) out[base + sidx[r]] = 0.0f;
    }
}

extern "C" void kernel_launch(void* const* d_in, const int* in_sizes, int n_in,
                              void* d_out, int out_size, void* d_ws, size_t ws_size,
                              hipStream_t stream) {
    const float* bbs  = (const float*)d_in[0];   // [B, N, 4] f32
    const float* conf = (const float*)d_in[1];   // [B, C, N] f32
    float* out = (float*)d_out;                  // [B, C, N] f32
    nms_kernel<<<dim3(BB * CC), dim3(256), 0, stream>>>(bbs, conf, out);
}

// Round 3
// 183.478 us; speedup vs baseline: 7.6229x; 6.1719x over previous
//
#include <hip/hip_runtime.h>

// NMS filter: B=8, C=20, N=2048.
// R3: boxes are shared across classes -> per-BATCH sparse IoU adjacency lists
// (kernel 1, 33M IoUs total), then per-(b,c) sort + graph-based greedy NMS
// (kernel 2, ~12K ops of suppression work instead of ~2M IoUs).

#define BB   8
#define CC   20
#define NBOX 2048
#define CAP  64            // max stored neighbors per box (mean degree ~6)
#define NMS_THR 0.45f
#define PRE_THR 0.005f

typedef unsigned long long u64;
typedef unsigned int u32;
typedef unsigned short u16;

__device__ __forceinline__ float area_rn(float x1, float y1, float x2, float y2) {
    return __fmul_rn(fmaxf(__fsub_rn(x2, x1), 0.f), fmaxf(__fsub_rn(y2, y1), 0.f));
}

__device__ __forceinline__ u64 shfl64(u64 v, int src) {
    u32 lo = __shfl((u32)v, src);
    u32 hi = __shfl((u32)(v >> 32), src);
    return ((u64)hi << 32) | lo;
}

// ---------------- Kernel 1: per-batch adjacency lists ----------------
// grid = 8 batches x 32 segments, block = 256. Each wave owns 16 rows.
__global__ __launch_bounds__(256) void adj_kernel(const float* __restrict__ bbs,
                                                  u32* __restrict__ deg,
                                                  u16* __restrict__ nbr) {
    const int batch = blockIdx.x >> 5;
    const int seg   = blockIdx.x & 31;
    const int lane  = threadIdx.x & 63;
    const int wv    = threadIdx.x >> 6;

    __shared__ float sx1[NBOX], sy1[NBOX], sx2[NBOX], sy2[NBOX], sar[NBOX]; // 40 KB

    const float4* bp = (const float4*)bbs + (size_t)batch * NBOX;
    for (int n = threadIdx.x; n < NBOX; n += 256) {
        float4 bv = bp[n];
        sx1[n] = bv.x; sy1[n] = bv.y; sx2[n] = bv.z; sy2[n] = bv.w;
        sar[n] = area_rn(bv.x, bv.y, bv.z, bv.w);
    }
    __syncthreads();

    for (int rr = 0; rr < 16; ++rr) {
        const int i = seg * 64 + wv * 16 + rr;
        const float px1 = sx1[i], py1 = sy1[i], px2 = sx2[i], py2 = sy2[i];
        const float par = sar[i];
        u32 hits = 0;
        #pragma unroll
        for (int k = 0; k < 32; ++k) {
            int c = lane + (k << 6);                      // bank-friendly stride 64
            float iw = fmaxf(__fsub_rn(fminf(px2, sx2[c]), fmaxf(px1, sx1[c])), 0.f);
            float ih = fmaxf(__fsub_rn(fminf(py2, sy2[c]), fmaxf(py1, sy1[c])), 0.f);
            float inter = __fmul_rn(iw, ih);
            float den = fmaxf(__fsub_rn(__fadd_rn(par, sar[c]), inter), 1e-12f);
            if (c != i && __fdiv_rn(inter, den) > NMS_THR) hits |= 1u << k;
        }
        int cnt = __popc(hits);
        int ofs = cnt;                                    // inclusive scan
        #pragma unroll
        for (int d = 1; d < 64; d <<= 1) {
            int v = __shfl_up(ofs, d);
            if (lane >= d) ofs += v;
        }
        int total = __shfl(ofs, 63);
        ofs -= cnt;                                       // exclusive
        u16* row = nbr + ((size_t)batch * NBOX + i) * CAP;
        while (hits) {
            int k = __ffs(hits) - 1; hits &= hits - 1;
            if (ofs < CAP) row[ofs] = (u16)(lane + (k << 6));
            ++ofs;
        }
        if (lane == 0) deg[batch * NBOX + i] = (u32)min(total, CAP);
    }
}

// ---------------- Kernel 2: per-(b,c) sort + graph greedy NMS ----------------
// grid = 160, block = 1024 (16 waves for sort width).
__global__ __launch_bounds__(1024) void nms_kernel(const float* __restrict__ conf,
                                                   const u32* __restrict__ deg,
                                                   const u16* __restrict__ nbr,
                                                   float* __restrict__ out) {
    const int wg   = blockIdx.x;
    const int b    = wg / CC;
    const int base = wg * NBOX;
    const int tid  = threadIdx.x;

    __shared__ union { u64 keys[NBOX]; u64 Mcol[NBOX]; } u;  // 16 KB (reused)
    __shared__ u16           sidx[NBOX];                      // 4 KB rank -> orig
    __shared__ u16           srank[NBOX];                     // 4 KB orig -> rank
    __shared__ unsigned char skeep[NBOX];                     // 2 KB

    // 1. composite keys: conf desc, tie -> orig idx asc
    for (int n = tid; n < NBOX; n += 1024) {
        u.keys[n] = ((u64)__float_as_uint(conf[base + n]) << 32) | (u32)(~n);
    }
    __syncthreads();

    // 2. bitonic sort desc (1024 pairs -> one per thread per pass)
    for (int k = 2; k <= NBOX; k <<= 1) {
        for (int j = k >> 1; j > 0; j >>= 1) {
            const int mask = j - 1;
            int i  = ((tid & ~mask) << 1) | (tid & mask);
            int ip = i + j;
            u64 a = u.keys[i], c2 = u.keys[ip];
            if ((a < c2) == ((i & k) == 0)) { u.keys[i] = c2; u.keys[ip] = a; }
            __syncthreads();
        }
    }

    // 3. extract; build rank maps; pre-threshold
    float cv[2]; int orig[2];
    #pragma unroll
    for (int p = 0; p < 2; ++p) {
        int r = tid + (p << 10);
        u64 key = u.keys[r];
        orig[p] = (int)(~(u32)key) & (NBOX - 1);
        cv[p]   = __uint_as_float((u32)(key >> 32));
        sidx[r] = (u16)orig[p];
        srank[orig[p]] = (u16)r;
        skeep[r] = (cv[p] > PRE_THR) ? 1 : 0;
    }
    __syncthreads();                                   // keys fully consumed

    // 4. per-rank within-chunk suppression masks from neighbor lists
    #pragma unroll
    for (int p = 0; p < 2; ++p) {
        int r = tid + (p << 10);
        int o = orig[p];
        int d = deg[b * NBOX + o];
        const u16* row = nbr + ((size_t)b * NBOX + o) * CAP;
        int cend = r | 63;
        u64 col = 0;
        for (int e = 0; e < d; ++e) {
            int rr = srank[row[e]];
            if (rr > r && rr <= cend) col |= 1ull << (rr & 63);
        }
        u.Mcol[r] = col;
    }
    __syncthreads();

    // 5. wave 0: serial greedy over 32 chunks, no internal barriers
    if (tid < 64) {
        const int lane = tid;
        for (int cb = 0; cb < NBOX; cb += 64) {
            int r = cb + lane;
            u64 alive = __ballot(skeep[r] != 0);
            u64 mc = u.Mcol[r];
            u64 haz = __ballot(mc != 0) & alive;       // alive pivots w/ in-chunk edges
            while (haz) {
                int l = __ffsll(haz) - 1; haz &= haz - 1;
                if ((alive >> l) & 1ull) {
                    u64 cl = shfl64(mc, l);
                    alive &= ~cl;
                    haz &= alive;
                }
            }
            skeep[r] = (unsigned char)((alive >> lane) & 1ull);
            if ((alive >> lane) & 1ull) {              // suppress later out-of-chunk nbrs
                int o = sidx[r];
                int d = deg[b * NBOX + o];
                const u16* row = nbr + ((size_t)b * NBOX + o) * CAP;
                for (int e = 0; e < d; ++e) {
                    int rr = srank[row[e]];
                    if (rr > (r | 63)) skeep[rr] = 0;
                }
            }
        }
    }
    __syncthreads();

    // 6. output: out[orig] = kept ? conf : 0
    #pragma unroll
    for (int p = 0; p < 2; ++p) {
        int r = tid + (p << 10);
        out[base + orig[p]] = skeep[r] ? cv[p] : 0.f;
    }
}

// ---------------- Fallback (R2 monolithic, used only if ws too small) ----------------
__global__ __launch_bounds__(256) void nms_mono(const float* __restrict__ bbs,
                                                const float* __restrict__ conf,
                                                float* __restrict__ out) {
    const int wg   = blockIdx.x;
    const int b    = wg / CC;
    const int base = wg * NBOX;
    const int tid  = threadIdx.x;
    const int lane = tid & 63;
    const int wv   = tid >> 6;

    __shared__ union {
        u64 keys[NBOX];
        struct { float x1[NBOX], y1[NBOX], x2[NBOX], y2[NBOX]; } a;
    } u;
    __shared__ u64           Mcol[NBOX];
    __shared__ int           sidx[NBOX];
    __shared__ unsigned char skeep[NBOX];

    for (int n = tid; n < NBOX; n += 256) {
        float cvv = conf[base + n];
        u.keys[n] = ((u64)__float_as_uint(cvv) << 32) | (u32)(~n);
    }
    __syncthreads();
    for (int k = 2; k <= NBOX; k <<= 1)
        for (int j = k >> 1; j > 0; j >>= 1) {
            const int mask = j - 1;
            for (int t = tid; t < NBOX / 2; t += 256) {
                int i = ((t & ~mask) << 1) | (t & mask), ip = i + j;
                u64 a = u.keys[i], c2 = u.keys[ip];
                if ((a < c2) == ((i & k) == 0)) { u.keys[i] = c2; u.keys[ip] = a; }
            }
            __syncthreads();
        }
    u64 myk[8];
    #pragma unroll
    for (int p = 0; p < 8; ++p) myk[p] = u.keys[tid + p * 256];
    __syncthreads();
    #pragma unroll
    for (int p = 0; p < 8; ++p) {
        int r = tid + p * 256;
        u64 key = myk[p];
        int idx = (int)(~(u32)key) & (NBOX - 1);
        float cvv = __uint_as_float((u32)(key >> 32));
        float4 bv = ((const float4*)bbs)[b * NBOX + idx];
        u.a.x1[r] = bv.x; u.a.y1[r] = bv.y; u.a.x2[r] = bv.z; u.a.y2[r] = bv.w;
        sidx[r] = idx;
        skeep[r] = (cvv > PRE_THR) ? 1 : 0;
        out[base + idx] = cvv;
    }
    __syncthreads();
    for (int c = wv; c < NBOX / 64; c += 4) {
        int r = c * 64 + lane;
        float bx1 = u.a.x1[r], by1 = u.a.y1[r], bx2 = u.a.x2[r], by2 = u.a.y2[r];
        float bar = area_rn(bx1, by1, bx2, by2);
        u64 col = 0;
        for (int s = 1; s < 64; ++s) {
            int src = (lane + s) & 63;
            float px1 = __shfl(bx1, src), py1 = __shfl(by1, src);
            float px2 = __shfl(bx2, src), py2 = __shfl(by2, src);
            float par = area_rn(px1, py1, px2, py2);
            float iw = fmaxf(__fsub_rn(fminf(px2, bx2), fmaxf(px1, bx1)), 0.f);
            float ih = fmaxf(__fsub_rn(fminf(py2, by2), fmaxf(py1, by1)), 0.f);
            float inter = __fmul_rn(iw, ih);
            float den = fmaxf(__fsub_rn(__fadd_rn(bar, par), inter), 1e-12f);
            if ((__fdiv_rn(inter, den) > NMS_THR) && (src > lane)) col |= 1ull << src;
        }
        Mcol[r] = col;
    }
    __syncthreads();
    for (int cb = 0; cb < NBOX; cb += 64) {
        bool k0 = skeep[cb + lane] != 0;
        u64 alive = __ballot(k0);
        if (alive)
            for (int l = 0; l < 64; ++l) {
                u64 cl = Mcol[cb + l];
                u64 take = (u64)0 - ((alive >> l) & 1ull);
                alive &= ~(cl & take);
            }
        if (tid < 64) skeep[cb + lane] = (unsigned char)((alive >> lane) & 1ull);
        if (alive)
            for (int jb = cb + 64 + wv * 64; jb < NBOX; jb += 256) {
                int jj = jb + lane;
                bool jk = skeep[jj] != 0;
                if (__ballot(jk)) {
                    float jx1 = u.a.x1[jj], jy1 = u.a.y1[jj];
                    float jx2 = u.a.x2[jj], jy2 = u.a.y2[jj];
                    float jar = area_rn(jx1, jy1, jx2, jy2);
                    bool dead = false;
                    u64 m = alive;
                    while (m) {
                        int l = __ffsll(m) - 1; m &= m - 1;
                        int r = cb + l;
                        float px1 = u.a.x1[r], py1 = u.a.y1[r];
                        float px2 = u.a.x2[r], py2 = u.a.y2[r];
                        float par = area_rn(px1, py1, px2, py2);
                        float iw = fmaxf(__fsub_rn(fminf(px2, jx2), fmaxf(px1, jx1)), 0.f);
                        float ih = fmaxf(__fsub_rn(fminf(py2, jy2), fmaxf(py1, jy1)), 0.f);
                        float inter = __fmul_rn(iw, ih);
                        float den = fmaxf(__fsub_rn(__fadd_rn(par, jar), inter), 1e-12f);
                        dead = dead | (__fdiv_rn(inter, den) > NMS_THR);
                    }
                    if (jk && dead) skeep[jj] = 0;
                }
            }
        __syncthreads();
    }
    #pragma unroll
    for (int p = 0; p < 8; ++p) {
        int r = tid + p * 256;
        if (!skeep[r]) out[base + sidx[r]] = 0.0f;
    }
}

extern "C" void kernel_launch(void* const* d_in, const int* in_sizes, int n_in,
                              void* d_out, int out_size, void* d_ws, size_t ws_size,
                              hipStream_t stream) {
    const float* bbs  = (const float*)d_in[0];   // [B, N, 4]
    const float* conf = (const float*)d_in[1];   // [B, C, N]
    float* out = (float*)d_out;                  // [B, C, N]

    const size_t deg_bytes = (size_t)BB * NBOX * sizeof(u32);          // 64 KB
    const size_t nbr_bytes = (size_t)BB * NBOX * CAP * sizeof(u16);    // 2 MB
    if (ws_size >= deg_bytes + nbr_bytes) {
        u32* deg = (u32*)d_ws;
        u16* nbr = (u16*)((char*)d_ws + deg_bytes);
        adj_kernel<<<dim3(BB * 32), dim3(256), 0, stream>>>(bbs, deg, nbr);
        nms_kernel<<<dim3(BB * CC), dim3(1024), 0, stream>>>(conf, deg, nbr, out);
    } else {
        nms_mono<<<dim3(BB * CC), dim3(256), 0, stream>>>(bbs, conf, out);
    }
}

// Round 4
// 109.848 us; speedup vs baseline: 12.7325x; 1.6703x over previous
//
#include <hip/hip_runtime.h>

// NMS filter: B=8, C=20, N=2048.
// R4: (1) adj_kernel: per-batch sparse IoU adjacency, row-register/column-LDS
//     tiling (DS instrs cut ~30x), exact divide-free IoU predicate:
//       RN(inter/den) > 0.45f  <=>  (double)inter > M*(double)den,
//       M = 0x1.CCCCCDp-2 (midpoint above 0.45f; product exact in f64).
// (2) prop_kernel: NO SORT. Greedy NMS == lex-first MIS: box alive iff all
//     higher-key IoU-neighbors dead. Parallel fixpoint propagation, ~20 rounds.

#define BB   8
#define CC   20
#define NBOX 2048
#define CAP  64
#define PRE_THR 0.005f
#define IOU_M 0x1.CCCCCDp-2   // double, exactly 30198989 * 2^-26

typedef unsigned long long u64;
typedef unsigned int u32;
typedef unsigned short u16;

__device__ __forceinline__ float area_rn(float x1, float y1, float x2, float y2) {
    return __fmul_rn(fmaxf(__fsub_rn(x2, x1), 0.f), fmaxf(__fsub_rn(y2, y1), 0.f));
}
// exact: equivalent to __fdiv_rn(inter,den) > 0.45f for den>0 finite
__device__ __forceinline__ bool iou_gt(float inter, float den) {
    return (double)inter > IOU_M * (double)den;
}

// ---------------- Kernel 1: per-batch adjacency lists ----------------
// grid = 8 batches x 32 row-segments (64 rows), block = 1024 (16 waves).
// Each wave: 4 row boxes in registers; column boxes read once from LDS per
// 4 rows (b128 + b32). Divide-free IoU predicate.
__global__ __launch_bounds__(1024) void adj_kernel(const float4* __restrict__ bbs,
                                                   u32* __restrict__ deg,
                                                   u16* __restrict__ nbr) {
    const int batch = blockIdx.x >> 5;
    const int seg   = blockIdx.x & 31;
    const int lane  = threadIdx.x & 63;
    const int wv    = threadIdx.x >> 6;

    __shared__ float4 sbox[NBOX];  // 32 KB
    __shared__ float  sar[NBOX];   // 8 KB

    const float4* bp = bbs + (size_t)batch * NBOX;
    for (int n = threadIdx.x; n < NBOX; n += 1024) {
        float4 bv = bp[n];
        sbox[n] = bv;
        sar[n]  = area_rn(bv.x, bv.y, bv.z, bv.w);
    }
    __syncthreads();

    const int r0 = seg * 64 + wv * 4;               // this wave's 4 rows
    float4 rb[4]; float ra[4]; u32 hits[4] = {0, 0, 0, 0};
    #pragma unroll
    for (int t = 0; t < 4; ++t) { rb[t] = sbox[r0 + t]; ra[t] = sar[r0 + t]; }

    #pragma unroll 4
    for (int k = 0; k < 32; ++k) {
        const int c = lane + (k << 6);
        const float4 cb = sbox[c];
        const float  ca = sar[c];
        #pragma unroll
        for (int t = 0; t < 4; ++t) {
            float iw = fmaxf(__fsub_rn(fminf(rb[t].z, cb.z), fmaxf(rb[t].x, cb.x)), 0.f);
            float ih = fmaxf(__fsub_rn(fminf(rb[t].w, cb.w), fmaxf(rb[t].y, cb.y)), 0.f);
            float inter = __fmul_rn(iw, ih);
            float den = fmaxf(__fsub_rn(__fadd_rn(ra[t], ca), inter), 1e-12f);
            if (c != r0 + t && iou_gt(inter, den)) hits[t] |= 1u << k;
        }
    }

    #pragma unroll
    for (int t = 0; t < 4; ++t) {
        const int i = r0 + t;
        int cnt = __popc(hits[t]);
        int ofs = cnt;                               // inclusive scan over lanes
        #pragma unroll
        for (int d = 1; d < 64; d <<= 1) {
            int v = __shfl_up(ofs, d);
            if (lane >= d) ofs += v;
        }
        int total = __shfl(ofs, 63);
        ofs -= cnt;                                  // exclusive
        u16* row = nbr + ((size_t)batch * NBOX + i) * CAP;
        u32 h = hits[t];
        while (h) {
            int k = __ffs(h) - 1; h &= h - 1;
            if (ofs < CAP) row[ofs] = (u16)(lane + (k << 6));
            ++ofs;
        }
        if (lane == 0) deg[batch * NBOX + i] = (u32)min(total, CAP);
    }
}

// ---------------- Kernel 2: sort-free greedy NMS via fixpoint propagation ----
// grid = 160, block = 256 (8 nodes/thread).
// state: 0 = undecided, 1 = alive, 2 = dead.
// Node alive iff all higher-key neighbors dead; dead iff any higher-key alive.
// Monotone: stale reads only delay convergence, never corrupt it. Progress
// guaranteed (max-key undecided node always decides each round).
__global__ __launch_bounds__(256) void prop_kernel(const float* __restrict__ conf,
                                                   const u32* __restrict__ deg,
                                                   const u16* __restrict__ nbr,
                                                   float* __restrict__ out) {
    const int wg   = blockIdx.x;
    const int b    = wg / CC;
    const int base = wg * NBOX;
    const int tid  = threadIdx.x;

    __shared__ u64           skey[NBOX];     // 16 KB: (conf_bits<<32)|~idx
    __shared__ unsigned char sstate[NBOX];   // 2 KB
    __shared__ int sflag;

    const u32* degb = deg + b * NBOX;
    const u16* nbrb = nbr + (size_t)b * NBOX * CAP;

    float cv[8]; u32 dreg[8]; u32 und = 0;
    #pragma unroll
    for (int p = 0; p < 8; ++p) {
        const int i = tid + (p << 8);
        float c = conf[base + i];
        cv[p] = c;
        dreg[p] = degb[i];
        skey[i] = ((u64)__float_as_uint(c) << 32) | (u32)(~i);
        bool live = (c > PRE_THR);
        sstate[i] = live ? 0 : 2;
        if (live) und |= 1u << p;
    }
    if (tid == 0) sflag = 0;
    __syncthreads();

    while (true) {
        bool changed = false;
        u32 m = und;
        while (m) {
            const int p = __ffs(m) - 1; m &= m - 1;
            const int i = tid + (p << 8);
            const u64 ki = skey[i];
            const int d  = (int)dreg[p];
            const u16* row = nbrb + (size_t)i * CAP;
            int verdict = 1;                          // alive unless told otherwise
            for (int e = 0; e < d; ++e) {
                const int j = row[e];
                if (skey[j] > ki) {
                    const int st = sstate[j];
                    if (st == 1) { verdict = 2; break; }   // higher alive -> dead
                    if (st == 0) verdict = 0;              // still pending
                }
            }
            if (verdict != 0) {
                sstate[i] = (unsigned char)verdict;
                und &= ~(1u << p);
                changed = true;
            }
        }
        if (changed) sflag = 1;
        __syncthreads();                              // (c) round writes visible
        const int f = sflag;
        __syncthreads();                              // (d) everyone has read f
        if (!f) break;
        if (tid == 0) sflag = 0;
        __syncthreads();                              // (e) reset visible
    }

    #pragma unroll
    for (int p = 0; p < 8; ++p) {
        const int i = tid + (p << 8);
        out[base + i] = (sstate[i] == 1) ? cv[p] : 0.f;
    }
}

// ---------------- Fallback (R2 monolithic, used only if ws too small) --------
#define NMS_THR 0.45f
__global__ __launch_bounds__(256) void nms_mono(const float* __restrict__ bbs,
                                                const float* __restrict__ conf,
                                                float* __restrict__ out) {
    const int wg   = blockIdx.x;
    const int b    = wg / CC;
    const int base = wg * NBOX;
    const int tid  = threadIdx.x;
    const int lane = tid & 63;
    const int wv   = tid >> 6;

    __shared__ union {
        u64 keys[NBOX];
        struct { float x1[NBOX], y1[NBOX], x2[NBOX], y2[NBOX]; } a;
    } u;
    __shared__ u64           Mcol[NBOX];
    __shared__ int           sidx[NBOX];
    __shared__ unsigned char skeep[NBOX];

    for (int n = tid; n < NBOX; n += 256) {
        float cvv = conf[base + n];
        u.keys[n] = ((u64)__float_as_uint(cvv) << 32) | (u32)(~n);
    }
    __syncthreads();
    for (int k = 2; k <= NBOX; k <<= 1)
        for (int j = k >> 1; j > 0; j >>= 1) {
            const int mask = j - 1;
            for (int t = tid; t < NBOX / 2; t += 256) {
                int i = ((t & ~mask) << 1) | (t & mask), ip = i + j;
                u64 a = u.keys[i], c2 = u.keys[ip];
                if ((a < c2) == ((i & k) == 0)) { u.keys[i] = c2; u.keys[ip] = a; }
            }
            __syncthreads();
        }
    u64 myk[8];
    #pragma unroll
    for (int p = 0; p < 8; ++p) myk[p] = u.keys[tid + p * 256];
    __syncthreads();
    #pragma unroll
    for (int p = 0; p < 8; ++p) {
        int r = tid + p * 256;
        u64 key = myk[p];
        int idx = (int)(~(u32)key) & (NBOX - 1);
        float cvv = __uint_as_float((u32)(key >> 32));
        float4 bv = ((const float4*)bbs)[b * NBOX + idx];
        u.a.x1[r] = bv.x; u.a.y1[r] = bv.y; u.a.x2[r] = bv.z; u.a.y2[r] = bv.w;
        sidx[r] = idx;
        skeep[r] = (cvv > PRE_THR) ? 1 : 0;
        out[base + idx] = cvv;
    }
    __syncthreads();
    for (int c = wv; c < NBOX / 64; c += 4) {
        int r = c * 64 + lane;
        float bx1 = u.a.x1[r], by1 = u.a.y1[r], bx2 = u.a.x2[r], by2 = u.a.y2[r];
        float bar = area_rn(bx1, by1, bx2, by2);
        u64 col = 0;
        for (int s = 1; s < 64; ++s) {
            int src = (lane + s) & 63;
            float px1 = __shfl(bx1, src), py1 = __shfl(by1, src);
            float px2 = __shfl(bx2, src), py2 = __shfl(by2, src);
            float par = area_rn(px1, py1, px2, py2);
            float iw = fmaxf(__fsub_rn(fminf(px2, bx2), fmaxf(px1, bx1)), 0.f);
            float ih = fmaxf(__fsub_rn(fminf(py2, by2), fmaxf(py1, by1)), 0.f);
            float inter = __fmul_rn(iw, ih);
            float den = fmaxf(__fsub_rn(__fadd_rn(bar, par), inter), 1e-12f);
            if ((__fdiv_rn(inter, den) > NMS_THR) && (src > lane)) col |= 1ull << src;
        }
        Mcol[r] = col;
    }
    __syncthreads();
    for (int cb = 0; cb < NBOX; cb += 64) {
        bool k0 = skeep[cb + lane] != 0;
        u64 alive = __ballot(k0);
        if (alive)
            for (int l = 0; l < 64; ++l) {
                u64 cl = Mcol[cb + l];
                u64 take = (u64)0 - ((alive >> l) & 1ull);
                alive &= ~(cl & take);
            }
        if (tid < 64) skeep[cb + lane] = (unsigned char)((alive >> lane) & 1ull);
        if (alive)
            for (int jb = cb + 64 + wv * 64; jb < NBOX; jb += 256) {
                int jj = jb + lane;
                bool jk = skeep[jj] != 0;
                if (__ballot(jk)) {
                    float jx1 = u.a.x1[jj], jy1 = u.a.y1[jj];
                    float jx2 = u.a.x2[jj], jy2 = u.a.y2[jj];
                    float jar = area_rn(jx1, jy1, jx2, jy2);
                    bool dead = false;
                    u64 m = alive;
                    while (m) {
                        int l = __ffsll(m) - 1; m &= m - 1;
                        int r = cb + l;
                        float px1 = u.a.x1[r], py1 = u.a.y1[r];
                        float px2 = u.a.x2[r], py2 = u.a.y2[r];
                        float par = area_rn(px1, py1, px2, py2);
                        float iw = fmaxf(__fsub_rn(fminf(px2, jx2), fmaxf(px1, jx1)), 0.f);
                        float ih = fmaxf(__fsub_rn(fminf(py2, jy2), fmaxf(py1, jy1)), 0.f);
                        float inter = __fmul_rn(iw, ih);
                        float den = fmaxf(__fsub_rn(__fadd_rn(par, jar), inter), 1e-12f);
                        dead = dead | (__fdiv_rn(inter, den) > NMS_THR);
                    }
                    if (jk && dead) skeep[jj] = 0;
                }
            }
        __syncthreads();
    }
    #pragma unroll
    for (int p = 0; p < 8; ++p) {
        int r = tid + p * 256;
        if (!skeep[r]) out[base + sidx[r]] = 0.0f;
    }
}

extern "C" void kernel_launch(void* const* d_in, const int* in_sizes, int n_in,
                              void* d_out, int out_size, void* d_ws, size_t ws_size,
                              hipStream_t stream) {
    const float* bbs  = (const float*)d_in[0];   // [B, N, 4]
    const float* conf = (const float*)d_in[1];   // [B, C, N]
    float* out = (float*)d_out;                  // [B, C, N]

    const size_t deg_bytes = (size_t)BB * NBOX * sizeof(u32);        // 64 KB
    const size_t nbr_bytes = (size_t)BB * NBOX * CAP * sizeof(u16);  // 2 MB
    if (ws_size >= deg_bytes + nbr_bytes) {
        u32* deg = (u32*)d_ws;
        u16* nbr = (u16*)((char*)d_ws + deg_bytes);
        adj_kernel<<<dim3(BB * 32), dim3(1024), 0, stream>>>((const float4*)bbs, deg, nbr);
        prop_kernel<<<dim3(BB * CC), dim3(256), 0, stream>>>(conf, deg, nbr, out);
    } else {
        nms_mono<<<dim3(BB * CC), dim3(256), 0, stream>>>(bbs, conf, out);
    }
}